// Round 7
// baseline (309.914 us; speedup 1.0000x reference)
//
#include <hip/hip_runtime.h>
#include <cstdint>
#include <cstddef>

// DeformConv2d B=8 C=256 H=W=64 Cout=256 K=3 s=1 p=1 d=1
// Prepass: weight fp32 -> bf16 into d_ws (1.18 MB, L2-resident).
// Main: fused bilinear im2col + MFMA GEMM, with SOFTWARE-PIPELINED staging:
// 9-slot rotating payload (slot = tap kk). Per interp: consume slot i
// (issued one stage earlier), then re-issue slot i for the next stage.
// Stage = one channel (9 taps). Stage 3 issues stage 0 of the NEXT chunk,
// so those loads cross the barrier + MFMA phase (issue-early / T14).
// Tables: packed pair offsets oab in 9 named VGPRs; folded pair weights in LDS.
// Grid = (b, ho) = 512 blocks x 512 thr (8 waves). Block tile 256co x 64px.
// K ordering: k = c*9 + kk (matches weight [co][c][kk] flat layout).

#define B_   8
#define C_   256
#define H_   64
#define W_   64
#define CO_  256
#define KK_  9
#define CC   32              // channels per chunk
#define PADK 296             // padded k row (bf16): 592B rows, 16B-aligned

typedef short  short8   __attribute__((ext_vector_type(8)));
typedef float  f32x4    __attribute__((ext_vector_type(4)));
typedef float  f32x2    __attribute__((ext_vector_type(2)));

__device__ inline short f2bf(float f) {   // round-to-nearest-even fp32->bf16
    uint32_t u = __builtin_bit_cast(uint32_t, f);
    u += 0x7FFFu + ((u >> 16) & 1u);
    return (short)(u >> 16);
}

// ---- prepass: weight fp32 -> bf16 ----
__global__ __launch_bounds__(256) void w2bf(const float* __restrict__ w,
                                            short* __restrict__ wb, int n8) {
    const int i = blockIdx.x * 256 + threadIdx.x;
    if (i >= n8) return;
    const f32x4 a = *reinterpret_cast<const f32x4*>(w + i * 8);
    const f32x4 b = *reinterpret_cast<const f32x4*>(w + i * 8 + 4);
    short8 v;
#pragma unroll
    for (int j = 0; j < 4; ++j) { v[j] = f2bf(a[j]); v[j + 4] = f2bf(b[j]); }
    *reinterpret_cast<short8*>(wb + i * 8) = v;
}

// issue slot I from channel base XP (2 x 8B pair loads)
#define ISS(I, XP) { \
    __builtin_memcpy(&Plo##I, (XP) + (oab##I & 0xFFFFu), 8); \
    __builtin_memcpy(&Phi##I, (XP) + (oab##I >> 16), 8); }

// consume slot I (stage S of current chunk), then re-issue slot I from XP
#define CI(S, I, XP) { \
    const f32x4 wv = t_wv[I * 64 + lane]; \
    const float v = wv[0] * Plo##I[0] + wv[1] * Plo##I[1] \
                  + wv[2] * Phi##I[0] + wv[3] * Phi##I[1]; \
    cols[cbase + 9 * (S) + (I)] = f2bf(v); \
    ISS(I, XP) }

#define SB(S, XP) CI(S,0,XP) CI(S,1,XP) CI(S,2,XP) CI(S,3,XP) CI(S,4,XP) \
                  CI(S,5,XP) CI(S,6,XP) CI(S,7,XP) CI(S,8,XP)

#define XPC(C0, S) ((const char*)(x + ((size_t)(b * C_ + (C0) + 4 * wqs + (S)) << 12)))

__global__ __launch_bounds__(512, 2) void dcn_mfma(
    const float* __restrict__ x,
    const float* __restrict__ offset,
    const short* __restrict__ wbf,     // bf16 weight [256][2304]
    const float* __restrict__ bias,
    float* __restrict__ out)
{
    __shared__ uint32_t t_oab[KK_ * 64];   // packed pair offsets (build only)
    __shared__ f32x4    t_wv[KK_ * 64];    // folded pair weights
    __shared__ short    cols[64 * PADK];   // [px][k] bf16 columns, one chunk

    const int bid = blockIdx.x;            // 512 = 64 * 8
    const int ho  = bid & 63;
    const int b   = bid >> 6;

    const int t    = threadIdx.x;
    const int lane = t & 63;               // px = wo
    const int wave = t >> 6;

    // ---- bilinear tables: one entry per (kk, wo) ----
    for (int e = t; e < KK_ * 64; e += 512) {
        const int kk = e >> 6;
        const int wo = e & 63;
        const int ky = kk / 3, kx = kk % 3;
        const float offy = offset[(((b * 18) + kk * 2 + 0) * 64 + ho) * 64 + wo];
        const float offx = offset[(((b * 18) + kk * 2 + 1) * 64 + ho) * 64 + wo];
        const float py  = (float)(ho - 1 + ky) + offy;
        const float pxx = (float)(wo - 1 + kx) + offx;
        const float y0f = floorf(py), x0f = floorf(pxx);
        const float wy = py - y0f, wx = pxx - x0f;
        const int y0 = (int)y0f, x0 = (int)x0f;
        const int y1 = y0 + 1,   x1 = x0 + 1;
        const float vy0 = (y0 >= 0 && y0 < H_) ? 1.f : 0.f;
        const float vy1 = (y1 >= 0 && y1 < H_) ? 1.f : 0.f;
        const float vx0 = (x0 >= 0 && x0 < W_) ? 1.f : 0.f;
        const float vx1 = (x1 >= 0 && x1 < W_) ? 1.f : 0.f;
        const float wv0 = (1.f - wy) * (1.f - wx) * vy0 * vx0;
        const float wv1 = (1.f - wy) * wx         * vy0 * vx1;
        const float wv2 = wy         * (1.f - wx) * vy1 * vx0;
        const float wv3 = wy         * wx         * vy1 * vx1;
        const int y0c = min(max(y0, 0), H_ - 1);
        const int y1c = min(max(y1, 0), H_ - 1);
        const int x0c = min(max(x0, 0), W_ - 1);
        const int x1c = min(max(x1, 0), W_ - 1);
        const int pb  = min(max(x0, 0), W_ - 2);   // pair base (covers pb, pb+1)
        const float sA0 = (x0c == pb)     ? 1.f : 0.f;
        const float sB0 = (x1c == pb)     ? 1.f : 0.f;
        const float sA1 = (x0c == pb + 1) ? 1.f : 0.f;
        const float sB1 = (x1c == pb + 1) ? 1.f : 0.f;
        f32x4 wv;
        wv[0] = sA0 * wv0 + sB0 * wv1;   // lo[0]
        wv[1] = sA1 * wv0 + sB1 * wv1;   // lo[1]
        wv[2] = sA0 * wv2 + sB0 * wv3;   // hi[0]
        wv[3] = sA1 * wv2 + sB1 * wv3;   // hi[1]
        t_oab[e] = (uint32_t)((y0c * W_ + pb) * 4) |
                   ((uint32_t)((y1c * W_ + pb) * 4) << 16);
        t_wv[e] = wv;
    }
    __syncthreads();

    // ---- per-thread tap offsets in named registers (px = lane) ----
    const uint32_t oab0 = t_oab[0 * 64 + lane];
    const uint32_t oab1 = t_oab[1 * 64 + lane];
    const uint32_t oab2 = t_oab[2 * 64 + lane];
    const uint32_t oab3 = t_oab[3 * 64 + lane];
    const uint32_t oab4 = t_oab[4 * 64 + lane];
    const uint32_t oab5 = t_oab[5 * 64 + lane];
    const uint32_t oab6 = t_oab[6 * 64 + lane];
    const uint32_t oab7 = t_oab[7 * 64 + lane];
    const uint32_t oab8 = t_oab[8 * 64 + lane];

    f32x4 acc[4][2];   // [mt co][nt px]
#pragma unroll
    for (int i = 0; i < 4; ++i) { acc[i][0] = (f32x4)0.f; acc[i][1] = (f32x4)0.f; }

    const int wm = wave >> 1;          // co-64 group
    const int wn = wave & 1;           // px-32 group
    const int co0 = __builtin_amdgcn_readfirstlane(wm * 64);
    const int px0 = __builtin_amdgcn_readfirstlane(wn * 32);
    const int wqs = __builtin_amdgcn_readfirstlane(wave);   // scalar wave idx
    const int m_l = lane & 15;         // row/col index within 16x16 fragment
    const int k_l = (lane >> 4) << 3;  // 8 contiguous k per lane
    const int cbase = lane * PADK + wave * 36;   // this thread's cols region

    const short* wrow[4];
#pragma unroll
    for (int mt = 0; mt < 4; ++mt)
        wrow[mt] = wbf + (size_t)(co0 + mt * 16 + m_l) * (C_ * KK_);

    // ---- 9-slot payload (single rotating buffer) ----
    f32x2 Plo0, Plo1, Plo2, Plo3, Plo4, Plo5, Plo6, Plo7, Plo8;
    f32x2 Phi0, Phi1, Phi2, Phi3, Phi4, Phi5, Phi6, Phi7, Phi8;

    // prologue: issue stage 0 of chunk 0
    {
        const char* xp = XPC(0, 0);
        ISS(0, xp) ISS(1, xp) ISS(2, xp) ISS(3, xp) ISS(4, xp)
        ISS(5, xp) ISS(6, xp) ISS(7, xp) ISS(8, xp)
    }

    for (int c0 = 0; c0 < C_; c0 += CC) {
        const int cn = (c0 + CC < C_) ? c0 + CC : 0;   // wrap: extra loads, discarded
        { const char* xp = XPC(c0, 1); SB(0, xp) }
        { const char* xp = XPC(c0, 2); SB(1, xp) }
        { const char* xp = XPC(c0, 3); SB(2, xp) }
        { const char* xp = XPC(cn, 0); SB(3, xp) }     // issues cross barrier+MFMA
        __syncthreads();

        // ---- MFMA over 9 k-steps ----
#pragma unroll
        for (int s = 0; s < 9; ++s) {
            const int krow = s * 32 + k_l;
            const short8 bfA = *reinterpret_cast<const short8*>(
                &cols[(px0 + m_l) * PADK + krow]);
            const short8 bfB = *reinterpret_cast<const short8*>(
                &cols[(px0 + 16 + m_l) * PADK + krow]);
            const int kglob = c0 * 9 + krow;
#pragma unroll
            for (int mt = 0; mt < 4; ++mt) {
                const short8 af = *reinterpret_cast<const short8*>(wrow[mt] + kglob);
                acc[mt][0] = __builtin_amdgcn_mfma_f32_16x16x32_bf16(
                    af, bfA, acc[mt][0], 0, 0, 0);
                acc[mt][1] = __builtin_amdgcn_mfma_f32_16x16x32_bf16(
                    af, bfB, acc[mt][1], 0, 0, 0);
            }
        }
        __syncthreads();
    }

    // ---- epilogue: D mapping col=lane&15 (n=px), row=(lane>>4)*4+r (m=co) ----
    const int r0 = (lane >> 4) << 2;
#pragma unroll
    for (int mt = 0; mt < 4; ++mt) {
#pragma unroll
        for (int r = 0; r < 4; ++r) {
            const int co = co0 + mt * 16 + r0 + r;
            const float bv = bias[co];
            float* orow = out + ((size_t)(b * CO_ + co) * H_ + ho) * W_;
            orow[px0 + m_l]      = acc[mt][0][r] + bv;
            orow[px0 + 16 + m_l] = acc[mt][1][r] + bv;
        }
    }
}

extern "C" void kernel_launch(void* const* d_in, const int* in_sizes, int n_in,
                              void* d_out, int out_size, void* d_ws, size_t ws_size,
                              hipStream_t stream) {
    const float* x      = (const float*)d_in[0];
    const float* offset = (const float*)d_in[1];
    const float* weight = (const float*)d_in[2];
    const float* bias   = (const float*)d_in[3];
    float* out = (float*)d_out;
    short* wbf = (short*)d_ws;          // 589824 bf16 = 1.18 MB
    (void)in_sizes; (void)n_in; (void)out_size; (void)ws_size;

    const int n8 = (CO_ * C_ * KK_) / 8;        // 73728 short8 groups
    hipLaunchKernelGGL(w2bf, dim3((n8 + 255) / 256), dim3(256), 0, stream,
                       weight, wbf, n8);
    hipLaunchKernelGGL(dcn_mfma, dim3(64 * B_), dim3(512), 0, stream,
                       x, offset, wbf, bias, out);
}

// Round 8
// 169.288 us; speedup vs baseline: 1.8307x; 1.8307x over previous
//
#include <hip/hip_runtime.h>
#include <cstdint>
#include <cstddef>

// DeformConv2d B=8 C=256 H=W=64 Cout=256 K=3 s=1 p=1 d=1
// Round 8: NHWC-bf16 layout transform to kill divergent gathers.
//  Prepass 1: wperm_k  — weight fp32 -> bf16, permuted [co][chunk][kk][c_l]
//  Prepass 2: xpose    — x NCHW fp32 -> NHWC bf16 (xT[b][y][x][c], 16 MB)
//  Main: fused im2col + MFMA. Gather = 4 coalesced 16B loads per (px,tap,
//  ch-octet); per-batch xT = 2 MB -> L2-resident per XCD via b = bid&7.
//  cols k-ordering k' = kk*32 + c_l (matches permuted weights).
// Fallback (ws too small): round-6 proven kernel (1.18 MB ws).

#define B_   8
#define C_   256
#define H_   64
#define W_   64
#define CO_  256
#define KK_  9
#define PADK 296             // padded k row (bf16): 592B rows, 16B-aligned

typedef short  short8   __attribute__((ext_vector_type(8)));
typedef float  f32x4    __attribute__((ext_vector_type(4)));
typedef float  f32x2    __attribute__((ext_vector_type(2)));

__device__ inline short f2bf(float f) {   // round-to-nearest-even fp32->bf16
    uint32_t u = __builtin_bit_cast(uint32_t, f);
    u += 0x7FFFu + ((u >> 16) & 1u);
    return (short)(u >> 16);
}
__device__ inline float bf2f(short s) {
    return __builtin_bit_cast(float, (uint32_t)(uint16_t)s << 16);
}

// ---- prepass 1: weight fp32 -> bf16, permuted [co][ch][kk][c_l] ----
__global__ __launch_bounds__(256) void wperm_k(const float* __restrict__ w,
                                               short* __restrict__ wp) {
    const int i = blockIdx.x * 256 + threadIdx.x;   // 73728 octet tasks
    const int q  = i & 3;                // c_l octet
    const int kk = (i >> 2) % 9;
    const int ch = ((i >> 2) / 9) & 7;
    const int co = i / 288;
    short8 v;
#pragma unroll
    for (int j = 0; j < 8; ++j)
        v[j] = f2bf(w[((size_t)(co * C_) + ch * 32 + q * 8 + j) * KK_ + kk]);
    *reinterpret_cast<short8*>(wp + (size_t)i * 8) = v;
}

// ---- prepass 2: x NCHW fp32 -> NHWC bf16 ----
__global__ __launch_bounds__(256) void xpose(const float* __restrict__ x,
                                             short* __restrict__ xT) {
    __shared__ short tile[64 * 258];     // [xw][c], +2 pad vs bank conflicts
    const int bid = blockIdx.x;          // 512 = 64*8
    const int y = bid & 63;
    const int b = bid >> 6;
    const int t = threadIdx.x;
    const int c4 = t >> 6;               // 0..3 (wave-uniform)
    const int xw = t & 63;
    const float* src = x + (size_t)b * (C_ * H_ * W_) + (size_t)y * W_ + xw;
#pragma unroll 8
    for (int j = 0; j < 64; ++j) {
        const int c = j * 4 + c4;
        tile[xw * 258 + c] = f2bf(src[(size_t)c * (H_ * W_)]);
    }
    __syncthreads();
    short* dst = xT + ((size_t)(b * (H_ * W_)) + y * W_) * C_;
#pragma unroll
    for (int r = 0; r < 8; ++r) {
        const int idx = r * 256 + t;     // 0..2047 short8 groups
        const int xw2 = idx >> 5;
        const int c2  = (idx & 31) * 8;
        *reinterpret_cast<short8*>(dst + xw2 * C_ + c2) =
            *reinterpret_cast<const short8*>(&tile[xw2 * 258 + c2]);
    }
}

// ---- main: fused im2col (NHWC gathers) + MFMA ----
__global__ __launch_bounds__(512, 2) void dcn_mfma2(
    const short* __restrict__ xT,      // [b][y][x][c] bf16, 2MB/batch
    const float* __restrict__ offset,
    const short* __restrict__ wpm,     // [co][ch][kk][c_l] bf16
    const float* __restrict__ bias,
    float* __restrict__ out)
{
    __shared__ uint32_t t_pA[KK_ * 64];  // idx00 | idx01<<16  (pixel indices)
    __shared__ uint32_t t_pB[KK_ * 64];  // idx10 | idx11<<16
    __shared__ f32x4    t_wv[KK_ * 64];  // 4 corner weights (0 if invalid)
    __shared__ short    cols[64 * PADK]; // [px][k'] k' = kk*32 + c_l

    const int bid = blockIdx.x;          // 512
    const int b   = bid & 7;             // wgid%8 -> XCD affinity for batch
    const int ho  = bid >> 3;

    const int t    = threadIdx.x;
    const int lane = t & 63;
    const int wave = t >> 6;

    // ---- bilinear tables: one entry per (kk, wo) ----
    for (int e = t; e < KK_ * 64; e += 512) {
        const int kk = e >> 6;
        const int wo = e & 63;
        const int ky = kk / 3, kx = kk % 3;
        const float offy = offset[(((b * 18) + kk * 2 + 0) * 64 + ho) * 64 + wo];
        const float offx = offset[(((b * 18) + kk * 2 + 1) * 64 + ho) * 64 + wo];
        const float py  = (float)(ho - 1 + ky) + offy;
        const float pxx = (float)(wo - 1 + kx) + offx;
        const float y0f = floorf(py), x0f = floorf(pxx);
        const float wy = py - y0f, wx = pxx - x0f;
        const int y0 = (int)y0f, x0 = (int)x0f;
        const int y1 = y0 + 1,   x1 = x0 + 1;
        const float vy0 = (y0 >= 0 && y0 < H_) ? 1.f : 0.f;
        const float vy1 = (y1 >= 0 && y1 < H_) ? 1.f : 0.f;
        const float vx0 = (x0 >= 0 && x0 < W_) ? 1.f : 0.f;
        const float vx1 = (x1 >= 0 && x1 < W_) ? 1.f : 0.f;
        f32x4 wv;
        wv[0] = (1.f - wy) * (1.f - wx) * vy0 * vx0;
        wv[1] = (1.f - wy) * wx         * vy0 * vx1;
        wv[2] = wy         * (1.f - wx) * vy1 * vx0;
        wv[3] = wy         * wx         * vy1 * vx1;
        const int y0c = min(max(y0, 0), H_ - 1);
        const int y1c = min(max(y1, 0), H_ - 1);
        const int x0c = min(max(x0, 0), W_ - 1);
        const int x1c = min(max(x1, 0), W_ - 1);
        t_pA[e] = (uint32_t)(y0c * W_ + x0c) | ((uint32_t)(y0c * W_ + x1c) << 16);
        t_pB[e] = (uint32_t)(y1c * W_ + x0c) | ((uint32_t)(y1c * W_ + x1c) << 16);
        t_wv[e] = wv;
    }
    __syncthreads();

    f32x4 acc[4][2];   // [mt co][nt px]
#pragma unroll
    for (int i = 0; i < 4; ++i) { acc[i][0] = (f32x4)0.f; acc[i][1] = (f32x4)0.f; }

    const int wm = wave >> 1;          // co-64 group
    const int wn = wave & 1;           // px-32 group
    const int co0 = __builtin_amdgcn_readfirstlane(wm * 64);
    const int px0 = __builtin_amdgcn_readfirstlane(wn * 32);
    const int m_l = lane & 15;
    const int k_l = (lane >> 4) << 3;

    const short* wrow[4];
#pragma unroll
    for (int mt = 0; mt < 4; ++mt)
        wrow[mt] = wpm + (size_t)(co0 + mt * 16 + m_l) * (C_ * KK_);

    // staging ids: thread -> (px, ch-octet, tap-parity)
    const int soct  = t & 3;           // channel octet (8 ch)
    const int spx   = (t >> 2) & 63;   // px
    const int shalf = t >> 8;          // 0: taps 0,2,4,6,8  1: taps 1,3,5,7
    const int ntap  = 5 - shalf;
    const char* xq = (const char*)xT + ((size_t)b << 21) + soct * 16;

    for (int ch = 0; ch < 8; ++ch) {
        // ---- stage: 4 coalesced 16B corner loads per tap ----
        const char* xc = xq + ch * 64;
#pragma unroll
        for (int jj = 0; jj < 5; ++jj) {
            if (jj < ntap) {
                const int kk = 2 * jj + shalf;
                const int e  = kk * 64 + spx;
                const uint32_t pA = t_pA[e];
                const uint32_t pB = t_pB[e];
                const f32x4    wv = t_wv[e];
                short8 s00, s01, s10, s11;
                __builtin_memcpy(&s00, xc + (size_t)(pA & 0xFFFFu) * 512, 16);
                __builtin_memcpy(&s01, xc + (size_t)(pA >> 16)     * 512, 16);
                __builtin_memcpy(&s10, xc + (size_t)(pB & 0xFFFFu) * 512, 16);
                __builtin_memcpy(&s11, xc + (size_t)(pB >> 16)     * 512, 16);
                short8 vs;
#pragma unroll
                for (int j = 0; j < 8; ++j) {
                    const float v = wv[0] * bf2f(s00[j]) + wv[1] * bf2f(s01[j])
                                  + wv[2] * bf2f(s10[j]) + wv[3] * bf2f(s11[j]);
                    vs[j] = f2bf(v);
                }
                *reinterpret_cast<short8*>(
                    &cols[spx * PADK + kk * 32 + soct * 8]) = vs;
            }
        }
        __syncthreads();

        // ---- MFMA over 9 k-steps (k' = kk*32 + c_l) ----
#pragma unroll
        for (int s = 0; s < 9; ++s) {
            const int krow = s * 32 + k_l;
            const short8 bfA = *reinterpret_cast<const short8*>(
                &cols[(px0 + m_l) * PADK + krow]);
            const short8 bfB = *reinterpret_cast<const short8*>(
                &cols[(px0 + 16 + m_l) * PADK + krow]);
            const int kglob = ch * 288 + krow;
#pragma unroll
            for (int mt = 0; mt < 4; ++mt) {
                const short8 af = *reinterpret_cast<const short8*>(wrow[mt] + kglob);
                acc[mt][0] = __builtin_amdgcn_mfma_f32_16x16x32_bf16(
                    af, bfA, acc[mt][0], 0, 0, 0);
                acc[mt][1] = __builtin_amdgcn_mfma_f32_16x16x32_bf16(
                    af, bfB, acc[mt][1], 0, 0, 0);
            }
        }
        __syncthreads();
    }

    // ---- epilogue: D mapping col=lane&15 (n=px), row=(lane>>4)*4+r (m=co) ----
    const int r0 = (lane >> 4) << 2;
#pragma unroll
    for (int mt = 0; mt < 4; ++mt) {
#pragma unroll
        for (int r = 0; r < 4; ++r) {
            const int co = co0 + mt * 16 + r0 + r;
            const float bv = bias[co];
            float* orow = out + ((size_t)(b * CO_ + co) * H_ + ho) * W_;
            orow[px0 + m_l]      = acc[mt][0][r] + bv;
            orow[px0 + 16 + m_l] = acc[mt][1][r] + bv;
        }
    }
}

// ================= fallback (round-6 proven path, ws < 18 MB) =================
__global__ __launch_bounds__(256) void w2bf_fb(const float* __restrict__ w,
                                               short* __restrict__ wb, int n8) {
    const int i = blockIdx.x * 256 + threadIdx.x;
    if (i >= n8) return;
    const f32x4 a = *reinterpret_cast<const f32x4*>(w + (size_t)i * 8);
    const f32x4 bq = *reinterpret_cast<const f32x4*>(w + (size_t)i * 8 + 4);
    short8 v;
#pragma unroll
    for (int j = 0; j < 4; ++j) { v[j] = f2bf(a[j]); v[j + 4] = f2bf(bq[j]); }
    *reinterpret_cast<short8*>(wb + (size_t)i * 8) = v;
}

__global__ __launch_bounds__(512, 2) void dcn_mfma_fb(
    const float* __restrict__ x,
    const float* __restrict__ offset,
    const short* __restrict__ wbf,
    const float* __restrict__ bias,
    float* __restrict__ out)
{
    __shared__ uint32_t t_oab[KK_ * 64];
    __shared__ f32x4    t_wv[KK_ * 64];
    __shared__ short    cols[64 * PADK];

    const int bid = blockIdx.x;
    const int ho  = bid & 63;
    const int b   = bid >> 6;
    const int t    = threadIdx.x;
    const int lane = t & 63;
    const int wave = t >> 6;

    for (int e = t; e < KK_ * 64; e += 512) {
        const int kk = e >> 6;
        const int wo = e & 63;
        const int ky = kk / 3, kx = kk % 3;
        const float offy = offset[(((b * 18) + kk * 2 + 0) * 64 + ho) * 64 + wo];
        const float offx = offset[(((b * 18) + kk * 2 + 1) * 64 + ho) * 64 + wo];
        const float py  = (float)(ho - 1 + ky) + offy;
        const float pxx = (float)(wo - 1 + kx) + offx;
        const float y0f = floorf(py), x0f = floorf(pxx);
        const float wy = py - y0f, wx = pxx - x0f;
        const int y0 = (int)y0f, x0 = (int)x0f;
        const int y1 = y0 + 1,   x1 = x0 + 1;
        const float vy0 = (y0 >= 0 && y0 < H_) ? 1.f : 0.f;
        const float vy1 = (y1 >= 0 && y1 < H_) ? 1.f : 0.f;
        const float vx0 = (x0 >= 0 && x0 < W_) ? 1.f : 0.f;
        const float vx1 = (x1 >= 0 && x1 < W_) ? 1.f : 0.f;
        const float wv0 = (1.f - wy) * (1.f - wx) * vy0 * vx0;
        const float wv1 = (1.f - wy) * wx         * vy0 * vx1;
        const float wv2 = wy         * (1.f - wx) * vy1 * vx0;
        const float wv3 = wy         * wx         * vy1 * vx1;
        const int y0c = min(max(y0, 0), H_ - 1);
        const int y1c = min(max(y1, 0), H_ - 1);
        const int x0c = min(max(x0, 0), W_ - 1);
        const int x1c = min(max(x1, 0), W_ - 1);
        const int pb  = min(max(x0, 0), W_ - 2);
        const float sA0 = (x0c == pb)     ? 1.f : 0.f;
        const float sB0 = (x1c == pb)     ? 1.f : 0.f;
        const float sA1 = (x0c == pb + 1) ? 1.f : 0.f;
        const float sB1 = (x1c == pb + 1) ? 1.f : 0.f;
        f32x4 wv;
        wv[0] = sA0 * wv0 + sB0 * wv1;
        wv[1] = sA1 * wv0 + sB1 * wv1;
        wv[2] = sA0 * wv2 + sB0 * wv3;
        wv[3] = sA1 * wv2 + sB1 * wv3;
        t_oab[e] = (uint32_t)((y0c * W_ + pb) * 4) |
                   ((uint32_t)((y1c * W_ + pb) * 4) << 16);
        t_wv[e] = wv;
    }
    __syncthreads();

    f32x4 acc[4][2];
#pragma unroll
    for (int i = 0; i < 4; ++i) { acc[i][0] = (f32x4)0.f; acc[i][1] = (f32x4)0.f; }

    const int wm = wave >> 1;
    const int wn = wave & 1;
    const int co0 = __builtin_amdgcn_readfirstlane(wm * 64);
    const int px0 = __builtin_amdgcn_readfirstlane(wn * 32);
    const int wqs = __builtin_amdgcn_readfirstlane(wave);
    const int m_l = lane & 15;
    const int k_l = (lane >> 4) << 3;

    const short* wrow[4];
#pragma unroll
    for (int mt = 0; mt < 4; ++mt)
        wrow[mt] = wbf + (size_t)(co0 + mt * 16 + m_l) * (C_ * KK_);

    for (int c0 = 0; c0 < C_; c0 += 32) {
        const char* xp[4];
#pragma unroll
        for (int dc = 0; dc < 4; ++dc)
            xp[dc] = (const char*)(x + ((size_t)(b * C_ + c0 + 4 * wqs + dc) << 12));
#pragma unroll
        for (int j = 0; j < 9; ++j) {
            short vs[4];
#pragma unroll
            for (int jj = 0; jj < 4; ++jj) {
                const int idx = j * 4 + jj;
                const int dc  = idx / 9;
                const int kk  = idx % 9;
                const uint32_t oab = t_oab[kk * 64 + lane];
                const f32x4    wv  = t_wv[kk * 64 + lane];
                f32x2 lo, hi;
                __builtin_memcpy(&lo, xp[dc] + (oab & 0xFFFFu), 8);
                __builtin_memcpy(&hi, xp[dc] + (oab >> 16), 8);
                vs[jj] = f2bf(wv[0] * lo[0] + wv[1] * lo[1] +
                              wv[2] * hi[0] + wv[3] * hi[1]);
            }
            short* cw = &cols[lane * PADK + (wave * 9 + j) * 4];
            cw[0] = vs[0]; cw[1] = vs[1]; cw[2] = vs[2]; cw[3] = vs[3];
        }
        __syncthreads();
#pragma unroll
        for (int s = 0; s < 9; ++s) {
            const int krow = s * 32 + k_l;
            const short8 bfA = *reinterpret_cast<const short8*>(
                &cols[(px0 + m_l) * PADK + krow]);
            const short8 bfB = *reinterpret_cast<const short8*>(
                &cols[(px0 + 16 + m_l) * PADK + krow]);
            const int kglob = c0 * 9 + krow;
#pragma unroll
            for (int mt = 0; mt < 4; ++mt) {
                const short8 af = *reinterpret_cast<const short8*>(wrow[mt] + kglob);
                acc[mt][0] = __builtin_amdgcn_mfma_f32_16x16x32_bf16(
                    af, bfA, acc[mt][0], 0, 0, 0);
                acc[mt][1] = __builtin_amdgcn_mfma_f32_16x16x32_bf16(
                    af, bfB, acc[mt][1], 0, 0, 0);
            }
        }
        __syncthreads();
    }

    const int r0 = (lane >> 4) << 2;
#pragma unroll
    for (int mt = 0; mt < 4; ++mt) {
#pragma unroll
        for (int r = 0; r < 4; ++r) {
            const int co = co0 + mt * 16 + r0 + r;
            const float bv = bias[co];
            float* orow = out + ((size_t)(b * CO_ + co) * H_ + ho) * W_;
            orow[px0 + m_l]      = acc[mt][0][r] + bv;
            orow[px0 + 16 + m_l] = acc[mt][1][r] + bv;
        }
    }
}

extern "C" void kernel_launch(void* const* d_in, const int* in_sizes, int n_in,
                              void* d_out, int out_size, void* d_ws, size_t ws_size,
                              hipStream_t stream) {
    const float* x      = (const float*)d_in[0];
    const float* offset = (const float*)d_in[1];
    const float* weight = (const float*)d_in[2];
    const float* bias   = (const float*)d_in[3];
    float* out = (float*)d_out;
    (void)in_sizes; (void)n_in; (void)out_size;

    const size_t WPM_BYTES = (size_t)CO_ * C_ * KK_ * 2;          // 1,179,648
    const size_t XT_BYTES  = (size_t)B_ * H_ * W_ * C_ * 2;       // 16,777,216

    if (ws_size >= WPM_BYTES + XT_BYTES) {
        short* wpm = (short*)d_ws;
        short* xT  = (short*)((char*)d_ws + WPM_BYTES);
        hipLaunchKernelGGL(wperm_k, dim3(288), dim3(256), 0, stream, weight, wpm);
        hipLaunchKernelGGL(xpose,   dim3(512), dim3(256), 0, stream, x, xT);
        hipLaunchKernelGGL(dcn_mfma2, dim3(512), dim3(512), 0, stream,
                           xT, offset, wpm, bias, out);
    } else {
        short* wbf = (short*)d_ws;   // 1.18 MB
        hipLaunchKernelGGL(w2bf_fb, dim3(288), dim3(256), 0, stream,
                           weight, wbf, 73728);
        hipLaunchKernelGGL(dcn_mfma_fb, dim3(512), dim3(512), 0, stream,
                           x, offset, wbf, bias, out);
    }
}

// Round 9
// 110.105 us; speedup vs baseline: 2.8147x; 1.5375x over previous
//
#include <hip/hip_runtime.h>
#include <cstdint>
#include <cstddef>

// DeformConv2d B=8 C=256 H=W=64 Cout=256 K=3 s=1 p=1 d=1
// Round 9: NHWC-bf16 (round 8) + full occupancy.
//  Prepass 1: wperm_k — weight fp32 -> bf16, permuted [co][chunk][kk][c_l]
//  Prepass 2: xpose   — x NCHW fp32 -> NHWC bf16 (xT[b][y][x][c], 16 MB)
//  Main: 512 blocks x 1024 thr (16 waves). Wave w owns co [w*16, w*16+16)
//  x all 64 px -> weight rows read ONCE per block (dedup). 2 blocks/CU x
//  16 waves = 32 waves/CU = 100% occupancy; launch_bounds(1024,8) caps
//  VGPR at 64 (acc = 16 regs only).
// Fallback (ws too small): round-6 proven kernel.

#define B_   8
#define C_   256
#define H_   64
#define W_   64
#define CO_  256
#define KK_  9
#define PADK 296             // padded k row (bf16): 592B rows, 16B-aligned

typedef short  short8   __attribute__((ext_vector_type(8)));
typedef float  f32x4    __attribute__((ext_vector_type(4)));
typedef float  f32x2    __attribute__((ext_vector_type(2)));

__device__ inline short f2bf(float f) {   // round-to-nearest-even fp32->bf16
    uint32_t u = __builtin_bit_cast(uint32_t, f);
    u += 0x7FFFu + ((u >> 16) & 1u);
    return (short)(u >> 16);
}
__device__ inline float bf2f(short s) {
    return __builtin_bit_cast(float, (uint32_t)(uint16_t)s << 16);
}

// ---- prepass 1: weight fp32 -> bf16, permuted [co][ch][kk][c_l] ----
__global__ __launch_bounds__(256) void wperm_k(const float* __restrict__ w,
                                               short* __restrict__ wp) {
    const int i = blockIdx.x * 256 + threadIdx.x;   // 73728 octet tasks
    const int q  = i & 3;                // c_l octet
    const int kk = (i >> 2) % 9;
    const int ch = ((i >> 2) / 9) & 7;
    const int co = i / 288;
    short8 v;
#pragma unroll
    for (int j = 0; j < 8; ++j)
        v[j] = f2bf(w[((size_t)(co * C_) + ch * 32 + q * 8 + j) * KK_ + kk]);
    *reinterpret_cast<short8*>(wp + (size_t)i * 8) = v;
}

// ---- prepass 2: x NCHW fp32 -> NHWC bf16 ----
__global__ __launch_bounds__(256) void xpose(const float* __restrict__ x,
                                             short* __restrict__ xT) {
    __shared__ short tile[64 * 258];     // [xw][c], +2 pad vs bank conflicts
    const int bid = blockIdx.x;          // 512 = 64*8
    const int y = bid & 63;
    const int b = bid >> 6;
    const int t = threadIdx.x;
    const int c4 = t >> 6;               // 0..3 (wave-uniform)
    const int xw = t & 63;
    const float* src = x + (size_t)b * (C_ * H_ * W_) + (size_t)y * W_ + xw;
#pragma unroll 8
    for (int j = 0; j < 64; ++j) {
        const int c = j * 4 + c4;
        tile[xw * 258 + c] = f2bf(src[(size_t)c * (H_ * W_)]);
    }
    __syncthreads();
    short* dst = xT + ((size_t)(b * (H_ * W_)) + y * W_) * C_;
#pragma unroll
    for (int r = 0; r < 8; ++r) {
        const int idx = r * 256 + t;     // 0..2047 short8 groups
        const int xw2 = idx >> 5;
        const int c2  = (idx & 31) * 8;
        *reinterpret_cast<short8*>(dst + xw2 * C_ + c2) =
            *reinterpret_cast<const short8*>(&tile[xw2 * 258 + c2]);
    }
}

// ---- main: fused im2col (NHWC gathers) + MFMA, 16 waves, full occupancy ----
__global__ __launch_bounds__(1024, 8) void dcn_mfma3(
    const short* __restrict__ xT,      // [b][y][x][c] bf16, 2MB/batch
    const float* __restrict__ offset,
    const short* __restrict__ wpm,     // [co][ch][kk][c_l] bf16
    const float* __restrict__ bias,
    float* __restrict__ out)
{
    __shared__ uint32_t t_pA[KK_ * 64];  // idx00 | idx01<<16  (pixel indices)
    __shared__ uint32_t t_pB[KK_ * 64];  // idx10 | idx11<<16
    __shared__ f32x4    t_wv[KK_ * 64];  // 4 corner weights (0 if invalid)
    __shared__ short    cols[64 * PADK]; // [px][k'] k' = kk*32 + c_l

    const int bid = blockIdx.x;          // 512
    const int b   = bid & 7;             // wgid%8 -> XCD affinity for batch
    const int ho  = bid >> 3;

    const int t    = threadIdx.x;
    const int lane = t & 63;
    const int wave = t >> 6;             // 0..15

    // ---- bilinear tables: one entry per (kk, wo) ----
    if (t < KK_ * 64) {
        const int e  = t;
        const int kk = e >> 6;
        const int wo = e & 63;
        const int ky = kk / 3, kx = kk % 3;
        const float offy = offset[(((b * 18) + kk * 2 + 0) * 64 + ho) * 64 + wo];
        const float offx = offset[(((b * 18) + kk * 2 + 1) * 64 + ho) * 64 + wo];
        const float py  = (float)(ho - 1 + ky) + offy;
        const float pxx = (float)(wo - 1 + kx) + offx;
        const float y0f = floorf(py), x0f = floorf(pxx);
        const float wy = py - y0f, wx = pxx - x0f;
        const int y0 = (int)y0f, x0 = (int)x0f;
        const int y1 = y0 + 1,   x1 = x0 + 1;
        const float vy0 = (y0 >= 0 && y0 < H_) ? 1.f : 0.f;
        const float vy1 = (y1 >= 0 && y1 < H_) ? 1.f : 0.f;
        const float vx0 = (x0 >= 0 && x0 < W_) ? 1.f : 0.f;
        const float vx1 = (x1 >= 0 && x1 < W_) ? 1.f : 0.f;
        f32x4 wv;
        wv[0] = (1.f - wy) * (1.f - wx) * vy0 * vx0;
        wv[1] = (1.f - wy) * wx         * vy0 * vx1;
        wv[2] = wy         * (1.f - wx) * vy1 * vx0;
        wv[3] = wy         * wx         * vy1 * vx1;
        const int y0c = min(max(y0, 0), H_ - 1);
        const int y1c = min(max(y1, 0), H_ - 1);
        const int x0c = min(max(x0, 0), W_ - 1);
        const int x1c = min(max(x1, 0), W_ - 1);
        t_pA[e] = (uint32_t)(y0c * W_ + x0c) | ((uint32_t)(y0c * W_ + x1c) << 16);
        t_pB[e] = (uint32_t)(y1c * W_ + x0c) | ((uint32_t)(y1c * W_ + x1c) << 16);
        t_wv[e] = wv;
    }
    __syncthreads();

    f32x4 acc0 = (f32x4)0.f, acc1 = (f32x4)0.f, acc2 = (f32x4)0.f, acc3 = (f32x4)0.f;

    const int co0 = __builtin_amdgcn_readfirstlane(wave * 16);   // 16 co per wave
    const int m_l = lane & 15;
    const int k_l = (lane >> 4) << 3;

    const short* wrow = wpm + (size_t)(co0 + m_l) * (C_ * KK_);

    // staging ids: thread -> (px, ch-octet, tap-replica)
    const int soct = t & 3;              // channel octet (8 ch)
    const int spx  = (t >> 2) & 63;      // px
    const int srep = t >> 8;             // 0..3: taps {srep, srep+4, srep+8}
    const char* xq = (const char*)xT + ((size_t)b << 21) + soct * 16;

    for (int ch = 0; ch < 8; ++ch) {
        // ---- stage: 4 coalesced 16B corner loads per tap ----
        const char* xc = xq + ch * 64;
#pragma unroll
        for (int jj = 0; jj < 3; ++jj) {
            const int kk = srep + jj * 4;
            if (kk < KK_) {
                const int e  = kk * 64 + spx;
                const uint32_t pA = t_pA[e];
                const uint32_t pB = t_pB[e];
                const f32x4    wv = t_wv[e];
                short8 s00, s01, s10, s11;
                __builtin_memcpy(&s00, xc + (size_t)(pA & 0xFFFFu) * 512, 16);
                __builtin_memcpy(&s01, xc + (size_t)(pA >> 16)     * 512, 16);
                __builtin_memcpy(&s10, xc + (size_t)(pB & 0xFFFFu) * 512, 16);
                __builtin_memcpy(&s11, xc + (size_t)(pB >> 16)     * 512, 16);
                short8 vs;
#pragma unroll
                for (int j = 0; j < 8; ++j) {
                    const float v = wv[0] * bf2f(s00[j]) + wv[1] * bf2f(s01[j])
                                  + wv[2] * bf2f(s10[j]) + wv[3] * bf2f(s11[j]);
                    vs[j] = f2bf(v);
                }
                *reinterpret_cast<short8*>(
                    &cols[spx * PADK + kk * 32 + soct * 8]) = vs;
            }
        }
        __syncthreads();

        // ---- MFMA over 9 k-steps (k' = kk*32 + c_l) ----
#pragma unroll
        for (int s = 0; s < 9; ++s) {
            const int krow = s * 32 + k_l;
            const short8 af = *reinterpret_cast<const short8*>(
                wrow + ch * 288 + krow);
            const short8 bf0 = *reinterpret_cast<const short8*>(
                &cols[( 0 + m_l) * PADK + krow]);
            const short8 bf1 = *reinterpret_cast<const short8*>(
                &cols[(16 + m_l) * PADK + krow]);
            const short8 bf2 = *reinterpret_cast<const short8*>(
                &cols[(32 + m_l) * PADK + krow]);
            const short8 bf3 = *reinterpret_cast<const short8*>(
                &cols[(48 + m_l) * PADK + krow]);
            acc0 = __builtin_amdgcn_mfma_f32_16x16x32_bf16(af, bf0, acc0, 0, 0, 0);
            acc1 = __builtin_amdgcn_mfma_f32_16x16x32_bf16(af, bf1, acc1, 0, 0, 0);
            acc2 = __builtin_amdgcn_mfma_f32_16x16x32_bf16(af, bf2, acc2, 0, 0, 0);
            acc3 = __builtin_amdgcn_mfma_f32_16x16x32_bf16(af, bf3, acc3, 0, 0, 0);
        }
        __syncthreads();
    }

    // ---- epilogue: D mapping col=lane&15 (px), row=(lane>>4)*4+r (co) ----
    const int r0 = (lane >> 4) << 2;
#pragma unroll
    for (int r = 0; r < 4; ++r) {
        const int co = co0 + r0 + r;
        const float bv = bias[co];
        float* orow = out + ((size_t)(b * CO_ + co) * H_ + ho) * W_;
        orow[ 0 + m_l] = acc0[r] + bv;
        orow[16 + m_l] = acc1[r] + bv;
        orow[32 + m_l] = acc2[r] + bv;
        orow[48 + m_l] = acc3[r] + bv;
    }
}

// ================= fallback (round-6 proven path, ws < 18 MB) =================
__global__ __launch_bounds__(256) void w2bf_fb(const float* __restrict__ w,
                                               short* __restrict__ wb, int n8) {
    const int i = blockIdx.x * 256 + threadIdx.x;
    if (i >= n8) return;
    const f32x4 a = *reinterpret_cast<const f32x4*>(w + (size_t)i * 8);
    const f32x4 bq = *reinterpret_cast<const f32x4*>(w + (size_t)i * 8 + 4);
    short8 v;
#pragma unroll
    for (int j = 0; j < 4; ++j) { v[j] = f2bf(a[j]); v[j + 4] = f2bf(bq[j]); }
    *reinterpret_cast<short8*>(wb + (size_t)i * 8) = v;
}

__global__ __launch_bounds__(512, 2) void dcn_mfma_fb(
    const float* __restrict__ x,
    const float* __restrict__ offset,
    const short* __restrict__ wbf,
    const float* __restrict__ bias,
    float* __restrict__ out)
{
    __shared__ uint32_t t_oab[KK_ * 64];
    __shared__ f32x4    t_wv[KK_ * 64];
    __shared__ short    cols[64 * PADK];

    const int bid = blockIdx.x;
    const int ho  = bid & 63;
    const int b   = bid >> 6;
    const int t    = threadIdx.x;
    const int lane = t & 63;
    const int wave = t >> 6;

    for (int e = t; e < KK_ * 64; e += 512) {
        const int kk = e >> 6;
        const int wo = e & 63;
        const int ky = kk / 3, kx = kk % 3;
        const float offy = offset[(((b * 18) + kk * 2 + 0) * 64 + ho) * 64 + wo];
        const float offx = offset[(((b * 18) + kk * 2 + 1) * 64 + ho) * 64 + wo];
        const float py  = (float)(ho - 1 + ky) + offy;
        const float pxx = (float)(wo - 1 + kx) + offx;
        const float y0f = floorf(py), x0f = floorf(pxx);
        const float wy = py - y0f, wx = pxx - x0f;
        const int y0 = (int)y0f, x0 = (int)x0f;
        const int y1 = y0 + 1,   x1 = x0 + 1;
        const float vy0 = (y0 >= 0 && y0 < H_) ? 1.f : 0.f;
        const float vy1 = (y1 >= 0 && y1 < H_) ? 1.f : 0.f;
        const float vx0 = (x0 >= 0 && x0 < W_) ? 1.f : 0.f;
        const float vx1 = (x1 >= 0 && x1 < W_) ? 1.f : 0.f;
        const float wv0 = (1.f - wy) * (1.f - wx) * vy0 * vx0;
        const float wv1 = (1.f - wy) * wx         * vy0 * vx1;
        const float wv2 = wy         * (1.f - wx) * vy1 * vx0;
        const float wv3 = wy         * wx         * vy1 * vx1;
        const int y0c = min(max(y0, 0), H_ - 1);
        const int y1c = min(max(y1, 0), H_ - 1);
        const int x0c = min(max(x0, 0), W_ - 1);
        const int x1c = min(max(x1, 0), W_ - 1);
        const int pb  = min(max(x0, 0), W_ - 2);
        const float sA0 = (x0c == pb)     ? 1.f : 0.f;
        const float sB0 = (x1c == pb)     ? 1.f : 0.f;
        const float sA1 = (x0c == pb + 1) ? 1.f : 0.f;
        const float sB1 = (x1c == pb + 1) ? 1.f : 0.f;
        f32x4 wv;
        wv[0] = sA0 * wv0 + sB0 * wv1;
        wv[1] = sA1 * wv0 + sB1 * wv1;
        wv[2] = sA0 * wv2 + sB0 * wv3;
        wv[3] = sA1 * wv2 + sB1 * wv3;
        t_oab[e] = (uint32_t)((y0c * W_ + pb) * 4) |
                   ((uint32_t)((y1c * W_ + pb) * 4) << 16);
        t_wv[e] = wv;
    }
    __syncthreads();

    f32x4 acc[4][2];
#pragma unroll
    for (int i = 0; i < 4; ++i) { acc[i][0] = (f32x4)0.f; acc[i][1] = (f32x4)0.f; }

    const int wm = wave >> 1;
    const int wn = wave & 1;
    const int co0 = __builtin_amdgcn_readfirstlane(wm * 64);
    const int px0 = __builtin_amdgcn_readfirstlane(wn * 32);
    const int wqs = __builtin_amdgcn_readfirstlane(wave);
    const int m_l = lane & 15;
    const int k_l = (lane >> 4) << 3;

    const short* wrow[4];
#pragma unroll
    for (int mt = 0; mt < 4; ++mt)
        wrow[mt] = wbf + (size_t)(co0 + mt * 16 + m_l) * (C_ * KK_);

    for (int c0 = 0; c0 < C_; c0 += 32) {
        const char* xp[4];
#pragma unroll
        for (int dc = 0; dc < 4; ++dc)
            xp[dc] = (const char*)(x + ((size_t)(b * C_ + c0 + 4 * wqs + dc) << 12));
#pragma unroll
        for (int j = 0; j < 9; ++j) {
            short vs[4];
#pragma unroll
            for (int jj = 0; jj < 4; ++jj) {
                const int idx = j * 4 + jj;
                const int dc  = idx / 9;
                const int kk  = idx % 9;
                const uint32_t oab = t_oab[kk * 64 + lane];
                const f32x4    wv  = t_wv[kk * 64 + lane];
                f32x2 lo, hi;
                __builtin_memcpy(&lo, xp[dc] + (oab & 0xFFFFu), 8);
                __builtin_memcpy(&hi, xp[dc] + (oab >> 16), 8);
                vs[jj] = f2bf(wv[0] * lo[0] + wv[1] * lo[1] +
                              wv[2] * hi[0] + wv[3] * hi[1]);
            }
            short* cw = &cols[lane * PADK + (wave * 9 + j) * 4];
            cw[0] = vs[0]; cw[1] = vs[1]; cw[2] = vs[2]; cw[3] = vs[3];
        }
        __syncthreads();
#pragma unroll
        for (int s = 0; s < 9; ++s) {
            const int krow = s * 32 + k_l;
            const short8 bfA = *reinterpret_cast<const short8*>(
                &cols[(px0 + m_l) * PADK + krow]);
            const short8 bfB = *reinterpret_cast<const short8*>(
                &cols[(px0 + 16 + m_l) * PADK + krow]);
            const int kglob = c0 * 9 + krow;
#pragma unroll
            for (int mt = 0; mt < 4; ++mt) {
                const short8 af = *reinterpret_cast<const short8*>(wrow[mt] + kglob);
                acc[mt][0] = __builtin_amdgcn_mfma_f32_16x16x32_bf16(
                    af, bfA, acc[mt][0], 0, 0, 0);
                acc[mt][1] = __builtin_amdgcn_mfma_f32_16x16x32_bf16(
                    af, bfB, acc[mt][1], 0, 0, 0);
            }
        }
        __syncthreads();
    }

    const int r0 = (lane >> 4) << 2;
#pragma unroll
    for (int mt = 0; mt < 4; ++mt) {
#pragma unroll
        for (int r = 0; r < 4; ++r) {
            const int co = co0 + mt * 16 + r0 + r;
            const float bv = bias[co];
            float* orow = out + ((size_t)(b * CO_ + co) * H_ + ho) * W_;
            orow[px0 + m_l]      = acc[mt][0][r] + bv;
            orow[px0 + 16 + m_l] = acc[mt][1][r] + bv;
        }
    }
}

extern "C" void kernel_launch(void* const* d_in, const int* in_sizes, int n_in,
                              void* d_out, int out_size, void* d_ws, size_t ws_size,
                              hipStream_t stream) {
    const float* x      = (const float*)d_in[0];
    const float* offset = (const float*)d_in[1];
    const float* weight = (const float*)d_in[2];
    const float* bias   = (const float*)d_in[3];
    float* out = (float*)d_out;
    (void)in_sizes; (void)n_in; (void)out_size;

    const size_t WPM_BYTES = (size_t)CO_ * C_ * KK_ * 2;          // 1,179,648
    const size_t XT_BYTES  = (size_t)B_ * H_ * W_ * C_ * 2;       // 16,777,216

    if (ws_size >= WPM_BYTES + XT_BYTES) {
        short* wpm = (short*)d_ws;
        short* xT  = (short*)((char*)d_ws + WPM_BYTES);
        hipLaunchKernelGGL(wperm_k, dim3(288), dim3(256), 0, stream, weight, wpm);
        hipLaunchKernelGGL(xpose,   dim3(512), dim3(256), 0, stream, x, xT);
        hipLaunchKernelGGL(dcn_mfma3, dim3(512), dim3(1024), 0, stream,
                           xT, offset, wpm, bias, out);
    } else {
        short* wbf = (short*)d_ws;   // 1.18 MB
        hipLaunchKernelGGL(w2bf_fb, dim3(288), dim3(256), 0, stream,
                           weight, wbf, 73728);
        hipLaunchKernelGGL(dcn_mfma_fb, dim3(512), dim3(512), 0, stream,
                           x, offset, wbf, bias, out);
    }
}